// Round 3
// baseline (319.162 us; speedup 1.0000x reference)
//
#include <hip/hip_runtime.h>
#include <hip/hip_bf16.h>

#define D_MODEL 256
#define D_HID   128
#define SEQ     1024
#define NBATCH  32
#define NROWS   (NBATCH * SEQ)    // 32768
#define MASKV   -10000.0f
#define EPSLN   1e-5f

typedef unsigned short u16;
using bf16x8 = __attribute__((ext_vector_type(8))) short;   // 8 bf16 in 4 VGPRs
using f32x4  = __attribute__((ext_vector_type(4))) float;   // 4 fp32 acc

union U8 { uint4 v; u16 s[8]; };

__device__ __forceinline__ float bf2f(u16 u) {
    unsigned int x = ((unsigned int)u) << 16;
    return __uint_as_float(x);
}
__device__ __forceinline__ u16 f2bf(float f) {
    unsigned int u = __float_as_uint(f);
    u += 0x7fff + ((u >> 16) & 1);   // RNE
    return (u16)(u >> 16);
}

// 8-wide loaders returning fp32 lanes; fp32 source (two float4) or bf16 source
__device__ __forceinline__ void load8(const float* p, float* f) {
    float4 a = *(const float4*)p;
    float4 b = *(const float4*)(p + 4);
    f[0] = a.x; f[1] = a.y; f[2] = a.z; f[3] = a.w;
    f[4] = b.x; f[5] = b.y; f[6] = b.z; f[7] = b.w;
}
__device__ __forceinline__ void load8(const u16* p, float* f) {
    U8 u; u.v = *(const uint4*)p;
    #pragma unroll
    for (int e = 0; e < 8; e++) f[e] = bf2f(u.s[e]);
}
__device__ __forceinline__ void load4(const float* p, float* f) {
    float4 a = *(const float4*)p;
    f[0] = a.x; f[1] = a.y; f[2] = a.z; f[3] = a.w;
}
__device__ __forceinline__ void load4(const u16* p, float* f) {
    ushort4 v = *(const ushort4*)p;
    f[0] = bf2f(v.x); f[1] = bf2f(v.y); f[2] = bf2f(v.z); f[3] = bf2f(v.w);
}

// ---------------------------------------------------------------------------
// Weight transposes: fp32 W[K][N] -> bf16 WT[N][K] (16B b-frag rows)
// ---------------------------------------------------------------------------
__global__ __launch_bounds__(256) void transpose_weights(
    const float* __restrict__ wqkv, u16* __restrict__ wqkvT,
    const float* __restrict__ wproj, u16* __restrict__ wprojT,
    const float* __restrict__ wfc1, u16* __restrict__ wfc1T,
    const float* __restrict__ wfc2, u16* __restrict__ wfc2T) {
    int tid = blockIdx.x * 256 + threadIdx.x;
    int stride = gridDim.x * 256;
    for (int i = tid; i < 768 * 256; i += stride) {       // wqkv [256][768]
        int n = i >> 8, k = i & 255;
        wqkvT[i] = f2bf(wqkv[k * 768 + n]);
    }
    for (int i = tid; i < 256 * 256; i += stride) {       // wproj [256][256]
        int n = i >> 8, k = i & 255;
        wprojT[i] = f2bf(wproj[k * 256 + n]);
    }
    for (int i = tid; i < 128 * 256; i += stride) {       // wfc1 [256][128]
        int n = i >> 8, k = i & 255;
        wfc1T[i] = f2bf(wfc1[k * 128 + n]);
    }
    for (int i = tid; i < 256 * 128; i += stride) {       // wfc2 [128][256]
        int n = i >> 7, k = i & 127;
        wfc2T[i] = f2bf(wfc2[k * 256 + n]);
    }
}

// ---------------------------------------------------------------------------
// LN stats: one wave per row (256 cols, 4/lane) -> (mu, rstd)
// ---------------------------------------------------------------------------
template <typename TX>
__global__ __launch_bounds__(256) void ln_stats(
    const TX* __restrict__ x, float2* __restrict__ st) {
    int wave = threadIdx.x >> 6, lane = threadIdx.x & 63;
    int row = blockIdx.x * 4 + wave;
    float f[4];
    load4(x + (size_t)row * D_MODEL + lane * 4, f);
    float s  = f[0] + f[1] + f[2] + f[3];
    float sq = f[0] * f[0] + f[1] * f[1] + f[2] * f[2] + f[3] * f[3];
    #pragma unroll
    for (int off = 1; off < 64; off <<= 1) {
        s  += __shfl_xor(s, off);
        sq += __shfl_xor(sq, off);
    }
    float mu   = s * (1.0f / 256.0f);
    float var  = sq * (1.0f / 256.0f) - mu * mu;
    float rstd = rsqrtf(var + EPSLN);
    if (lane == 0) st[row] = make_float2(mu, rstd);
}

// ---------------------------------------------------------------------------
// 64x64 GEMM tile mainloops. 4 waves 2x2; each wave 32x32 (4 c-frags).
// K staged in 128-chunks; LDS rows padded +8 (2-way aliasing = free).
// ---------------------------------------------------------------------------
template <int K>
__device__ __forceinline__ void gemm_tile(
    const u16* __restrict__ A, const u16* __restrict__ BT,
    int m0, int n0, u16* lds, f32x4 acc[2][2]) {
    constexpr int KC = 128, KP = KC + 8;   // 136
    u16* ldsA = lds;
    u16* ldsB = lds + 64 * KP;
    const int tid = threadIdx.x;
    const int lane = tid & 63, wave = tid >> 6;
    const int wr = (wave >> 1) * 32, wc = (wave & 1) * 32;
    const int row = lane & 15, quad = lane >> 4;

    for (int ks = 0; ks < K; ks += KC) {
        __syncthreads();
        for (int i = tid; i < 64 * KC / 8; i += 256) {
            int i8 = i * 8;
            int r = i8 >> 7, c = i8 & 127;
            *(uint4*)(ldsA + r * KP + c) =
                *(const uint4*)(A + (size_t)(m0 + r) * K + ks + c);
            *(uint4*)(ldsB + r * KP + c) =
                *(const uint4*)(BT + (size_t)(n0 + r) * K + ks + c);
        }
        __syncthreads();
        #pragma unroll
        for (int k0 = 0; k0 < KC; k0 += 32) {
            bf16x8 a0 = *(const bf16x8*)(ldsA + (wr + row) * KP + k0 + quad * 8);
            bf16x8 a1 = *(const bf16x8*)(ldsA + (wr + 16 + row) * KP + k0 + quad * 8);
            bf16x8 b0 = *(const bf16x8*)(ldsB + (wc + row) * KP + k0 + quad * 8);
            bf16x8 b1 = *(const bf16x8*)(ldsB + (wc + 16 + row) * KP + k0 + quad * 8);
            acc[0][0] = __builtin_amdgcn_mfma_f32_16x16x32_bf16(a0, b0, acc[0][0], 0, 0, 0);
            acc[0][1] = __builtin_amdgcn_mfma_f32_16x16x32_bf16(a0, b1, acc[0][1], 0, 0, 0);
            acc[1][0] = __builtin_amdgcn_mfma_f32_16x16x32_bf16(a1, b0, acc[1][0], 0, 0, 0);
            acc[1][1] = __builtin_amdgcn_mfma_f32_16x16x32_bf16(a1, b1, acc[1][1], 0, 0, 0);
        }
    }
}

// LayerNorm fused into A-staging: row r of A is (x[r]-mu)*rstd*gamma+beta.
// TX = float (raw input x) or u16 (bf16 intermediate x2).
template <int K, typename TX>
__device__ __forceinline__ void gemm_tile_ln(
    const TX* __restrict__ X, const float2* __restrict__ st,
    const float* __restrict__ gamma, const float* __restrict__ beta,
    const u16* __restrict__ BT,
    int m0, int n0, u16* lds, f32x4 acc[2][2]) {
    constexpr int KC = 128, KP = KC + 8;
    u16* ldsA = lds;
    u16* ldsB = lds + 64 * KP;
    const int tid = threadIdx.x;
    const int lane = tid & 63, wave = tid >> 6;
    const int wr = (wave >> 1) * 32, wc = (wave & 1) * 32;
    const int row = lane & 15, quad = lane >> 4;

    for (int ks = 0; ks < K; ks += KC) {
        __syncthreads();
        for (int i = tid; i < 64 * KC / 8; i += 256) {
            int i8 = i * 8;
            int r = i8 >> 7, c = i8 & 127;
            float2 s2 = st[m0 + r];              // (mu, rstd)
            float xf[8], gf[8], bf[8];
            load8(X + (size_t)(m0 + r) * K + ks + c, xf);
            load8(gamma + ks + c, gf);
            load8(beta + ks + c, bf);
            U8 o;
            #pragma unroll
            for (int e = 0; e < 8; e++)
                o.s[e] = f2bf((xf[e] - s2.x) * s2.y * gf[e] + bf[e]);
            *(uint4*)(ldsA + r * KP + c) = o.v;
            *(uint4*)(ldsB + r * KP + c) =
                *(const uint4*)(BT + (size_t)(n0 + r) * K + ks + c);
        }
        __syncthreads();
        #pragma unroll
        for (int k0 = 0; k0 < KC; k0 += 32) {
            bf16x8 a0 = *(const bf16x8*)(ldsA + (wr + row) * KP + k0 + quad * 8);
            bf16x8 a1 = *(const bf16x8*)(ldsA + (wr + 16 + row) * KP + k0 + quad * 8);
            bf16x8 b0 = *(const bf16x8*)(ldsB + (wc + row) * KP + k0 + quad * 8);
            bf16x8 b1 = *(const bf16x8*)(ldsB + (wc + 16 + row) * KP + k0 + quad * 8);
            acc[0][0] = __builtin_amdgcn_mfma_f32_16x16x32_bf16(a0, b0, acc[0][0], 0, 0, 0);
            acc[0][1] = __builtin_amdgcn_mfma_f32_16x16x32_bf16(a0, b1, acc[0][1], 0, 0, 0);
            acc[1][0] = __builtin_amdgcn_mfma_f32_16x16x32_bf16(a1, b0, acc[1][0], 0, 0, 0);
            acc[1][1] = __builtin_amdgcn_mfma_f32_16x16x32_bf16(a1, b1, acc[1][1], 0, 0, 0);
        }
    }
}

#define ZERO_ACC(acc)                                        \
    _Pragma("unroll") for (int i_ = 0; i_ < 2; i_++)         \
    _Pragma("unroll") for (int j_ = 0; j_ < 2; j_++)         \
    _Pragma("unroll") for (int e_ = 0; e_ < 4; e_++) acc[i_][j_][e_] = 0.0f;

// QKV with fused LN1: LN(x) @ wqkv + b -> q[b,s,256], k[b,s,256], vT[b,256,s]
__global__ __launch_bounds__(256) void gemm_qkv(
    const float* __restrict__ x, const float2* __restrict__ st1,
    const float* __restrict__ g1, const float* __restrict__ be1,
    const u16* __restrict__ wqkvT, const float* __restrict__ b_qkv,
    u16* __restrict__ q, u16* __restrict__ kk, u16* __restrict__ vT) {
    __shared__ u16 lds[2 * 64 * 136];
    f32x4 acc[2][2];
    ZERO_ACC(acc)
    int m0 = blockIdx.x * 64, n0 = blockIdx.y * 64;
    gemm_tile_ln<256, float>(x, st1, g1, be1, wqkvT, m0, n0, lds, acc);
    int lane = threadIdx.x & 63, wave = threadIdx.x >> 6;
    int wr = (wave >> 1) * 32, wc = (wave & 1) * 32;
    int row = lane & 15, quad = lane >> 4;
    #pragma unroll
    for (int i = 0; i < 2; i++) {
        #pragma unroll
        for (int j = 0; j < 2; j++) {
            int gn = n0 + wc + j * 16 + row;
            float bias = b_qkv[gn];
            int gm = m0 + wr + i * 16 + quad * 4;   // rows gm..gm+3
            if (gn < 512) {
                u16* dst = (gn < 256) ? q : kk;
                int col = gn & 255;
                #pragma unroll
                for (int r = 0; r < 4; r++)
                    dst[(size_t)(gm + r) * 256 + col] = f2bf(acc[i][j][r] + bias);
            } else {
                int d = gn - 512;
                int b = gm >> 10, s = gm & 1023;    // 4 consecutive s
                ushort4 pack;
                pack.x = f2bf(acc[i][j][0] + bias);
                pack.y = f2bf(acc[i][j][1] + bias);
                pack.z = f2bf(acc[i][j][2] + bias);
                pack.w = f2bf(acc[i][j][3] + bias);
                *(ushort4*)(vT + ((size_t)(b * 256 + d) << 10) + s) = pack;
            }
        }
    }
}

// proj: ao @ wproj + b + residual(x fp32) -> x2 (bf16)
__global__ __launch_bounds__(256) void gemm_proj(
    const u16* __restrict__ ao, const u16* __restrict__ wprojT,
    const float* __restrict__ b_proj, const float* __restrict__ x_in,
    u16* __restrict__ x2) {
    __shared__ u16 lds[2 * 64 * 136];
    f32x4 acc[2][2];
    ZERO_ACC(acc)
    int m0 = blockIdx.x * 64, n0 = blockIdx.y * 64;
    gemm_tile<256>(ao, wprojT, m0, n0, lds, acc);
    int lane = threadIdx.x & 63, wave = threadIdx.x >> 6;
    int wr = (wave >> 1) * 32, wc = (wave & 1) * 32;
    int row = lane & 15, quad = lane >> 4;
    #pragma unroll
    for (int i = 0; i < 2; i++)
        #pragma unroll
        for (int j = 0; j < 2; j++) {
            int gn = n0 + wc + j * 16 + row;
            float bias = b_proj[gn];
            int gm = m0 + wr + i * 16 + quad * 4;
            #pragma unroll
            for (int r = 0; r < 4; r++) {
                size_t idx = (size_t)(gm + r) * 256 + gn;
                x2[idx] = f2bf(acc[i][j][r] + bias + x_in[idx]);
            }
        }
}

// fc1 with fused LN2: relu(LN(x2) @ wfc1 + b) -> a1 [32768,128]
__global__ __launch_bounds__(256) void gemm_fc1(
    const u16* __restrict__ x2, const float2* __restrict__ st2,
    const float* __restrict__ g2, const float* __restrict__ be2,
    const u16* __restrict__ wfc1T, const float* __restrict__ b_fc1,
    u16* __restrict__ a1) {
    __shared__ u16 lds[2 * 64 * 136];
    f32x4 acc[2][2];
    ZERO_ACC(acc)
    int m0 = blockIdx.x * 64, n0 = blockIdx.y * 64;
    gemm_tile_ln<256, u16>(x2, st2, g2, be2, wfc1T, m0, n0, lds, acc);
    int lane = threadIdx.x & 63, wave = threadIdx.x >> 6;
    int wr = (wave >> 1) * 32, wc = (wave & 1) * 32;
    int row = lane & 15, quad = lane >> 4;
    #pragma unroll
    for (int i = 0; i < 2; i++)
        #pragma unroll
        for (int j = 0; j < 2; j++) {
            int gn = n0 + wc + j * 16 + row;
            float bias = b_fc1[gn];
            int gm = m0 + wr + i * 16 + quad * 4;
            #pragma unroll
            for (int r = 0; r < 4; r++) {
                float v = acc[i][j][r] + bias;
                a1[(size_t)(gm + r) * 128 + gn] = f2bf(fmaxf(v, 0.0f));
            }
        }
}

// fc2: a1 @ wfc2 + b + residual(x2) -> out (fp32)
__global__ __launch_bounds__(256) void gemm_fc2(
    const u16* __restrict__ a1, const u16* __restrict__ wfc2T,
    const float* __restrict__ b_fc2, const u16* __restrict__ x2,
    float* __restrict__ out) {
    __shared__ u16 lds[2 * 64 * 136];
    f32x4 acc[2][2];
    ZERO_ACC(acc)
    int m0 = blockIdx.x * 64, n0 = blockIdx.y * 64;
    gemm_tile<128>(a1, wfc2T, m0, n0, lds, acc);
    int lane = threadIdx.x & 63, wave = threadIdx.x >> 6;
    int wr = (wave >> 1) * 32, wc = (wave & 1) * 32;
    int row = lane & 15, quad = lane >> 4;
    #pragma unroll
    for (int i = 0; i < 2; i++)
        #pragma unroll
        for (int j = 0; j < 2; j++) {
            int gn = n0 + wc + j * 16 + row;
            float bias = b_fc2[gn];
            int gm = m0 + wr + i * 16 + quad * 4;
            #pragma unroll
            for (int r = 0; r < 4; r++) {
                size_t idx = (size_t)(gm + r) * 256 + gn;
                out[idx] = acc[i][j][r] + bias + bf2f(x2[idx]);
            }
        }
}

// ---------------------------------------------------------------------------
// Flash-style causal attention, all-bf16 internal. Block = 4 waves, 64 q-rows
// (16/wave). ao may alias q: block (b,qt) reads only its own 64 q-rows (into
// registers at start) and writes only those same rows at the end.
// ---------------------------------------------------------------------------
__global__ __launch_bounds__(256) void attn_kernel(
    const u16* __restrict__ q, const u16* __restrict__ k,
    const u16* __restrict__ vT, u16* __restrict__ ao) {
    constexpr int KP2 = 264;   // K-tile row pad (256+8)
    constexpr int VP  = 40;    // V-tile row pad (32+8)
    constexpr int PP  = 40;    // P row pad
    __shared__ u16 k_lds[32 * KP2];
    __shared__ u16 v_lds[256 * VP];
    __shared__ u16 p_lds[4 * 16 * PP];

    int b = blockIdx.y, qt = blockIdx.x;
    int tid = threadIdx.x;
    int lane = tid & 63, wave = tid >> 6;
    int row = lane & 15, quad = lane >> 4;
    int q0 = qt * 64 + wave * 16;
    int q_hi = q0 + 15;

    const u16* qb = q + ((size_t)b << 10) * 256;
    const u16* kb = k + ((size_t)b << 10) * 256;
    const u16* vb = vT + (((size_t)b * 256) << 10);

    bf16x8 qf[8];
    #pragma unroll
    for (int kk = 0; kk < 8; kk++)
        qf[kk] = *(const bf16x8*)(qb + (size_t)(q0 + row) * 256 + kk * 32 + quad * 8);

    f32x4 o[16];
    #pragma unroll
    for (int n = 0; n < 16; n++)
        #pragma unroll
        for (int e = 0; e < 4; e++) o[n][e] = 0.0f;
    float m_i[4], l_i[4];
    #pragma unroll
    for (int r = 0; r < 4; r++) { m_i[r] = -1e30f; l_i[r] = 0.0f; }

    int nkt = 2 * (qt + 1);
    for (int kt = 0; kt < nkt; kt++) {
        int k0 = kt * 32;
        __syncthreads();   // previous tile's frag reads done
        for (int i = tid; i < 1024; i += 256) {     // K tile: 32 x 256
            int i8 = i * 8;
            int r = i8 >> 8, c = i8 & 255;
            *(uint4*)(k_lds + r * KP2 + c) =
                *(const uint4*)(kb + (size_t)(k0 + r) * 256 + c);
        }
        {   // V tile: vT row d=tid, cols k0..k0+31
            const uint4* src = (const uint4*)(vb + ((size_t)tid << 10) + k0);
            uint4* dst = (uint4*)(v_lds + tid * VP);
            dst[0] = src[0]; dst[1] = src[1]; dst[2] = src[2]; dst[3] = src[3];
        }
        __syncthreads();
        if (k0 > q_hi) continue;   // causal: nothing for this wave here

        f32x4 s0, s1;
        #pragma unroll
        for (int e = 0; e < 4; e++) { s0[e] = 0.0f; s1[e] = 0.0f; }
        #pragma unroll
        for (int kkk = 0; kkk < 8; kkk++) {
            bf16x8 b0 = *(const bf16x8*)(k_lds + row * KP2 + kkk * 32 + quad * 8);
            bf16x8 b1 = *(const bf16x8*)(k_lds + (16 + row) * KP2 + kkk * 32 + quad * 8);
            s0 = __builtin_amdgcn_mfma_f32_16x16x32_bf16(qf[kkk], b0, s0, 0, 0, 0);
            s1 = __builtin_amdgcn_mfma_f32_16x16x32_bf16(qf[kkk], b1, s1, 0, 0, 0);
        }
        float sv[2][4];
        int qrow_base = q0 + quad * 4;
        #pragma unroll
        for (int r = 0; r < 4; r++) {
            float v0 = s0[r] * 0.0625f, v1 = s1[r] * 0.0625f;
            if (k0 + row > qrow_base + r) v0 = MASKV;
            if (k0 + 16 + row > qrow_base + r) v1 = MASKV;
            sv[0][r] = v0; sv[1][r] = v1;
        }
        float alpha[4];
        #pragma unroll
        for (int r = 0; r < 4; r++) {
            float t = fmaxf(sv[0][r], sv[1][r]);
            t = fmaxf(t, __shfl_xor(t, 1));
            t = fmaxf(t, __shfl_xor(t, 2));
            t = fmaxf(t, __shfl_xor(t, 4));
            t = fmaxf(t, __shfl_xor(t, 8));
            float mnew = fmaxf(m_i[r], t);
            alpha[r] = __expf(m_i[r] - mnew);
            sv[0][r] = __expf(sv[0][r] - mnew);
            sv[1][r] = __expf(sv[1][r] - mnew);
            float ps = sv[0][r] + sv[1][r];
            ps += __shfl_xor(ps, 1);
            ps += __shfl_xor(ps, 2);
            ps += __shfl_xor(ps, 4);
            ps += __shfl_xor(ps, 8);
            l_i[r] = l_i[r] * alpha[r] + ps;
            m_i[r] = mnew;
        }
        #pragma unroll
        for (int n = 0; n < 16; n++)
            #pragma unroll
            for (int r = 0; r < 4; r++) o[n][r] *= alpha[r];
        // P: C-layout -> LDS -> A-layout (same-wave DS ops; private region)
        u16* pw = p_lds + wave * 16 * PP;
        #pragma unroll
        for (int j = 0; j < 2; j++)
            #pragma unroll
            for (int r = 0; r < 4; r++)
                pw[(quad * 4 + r) * PP + j * 16 + row] = f2bf(sv[j][r]);
        bf16x8 pf = *(const bf16x8*)(pw + row * PP + quad * 8);
        #pragma unroll
        for (int n = 0; n < 16; n++) {
            bf16x8 bv = *(const bf16x8*)(v_lds + (n * 16 + row) * VP + quad * 8);
            o[n] = __builtin_amdgcn_mfma_f32_16x16x32_bf16(pf, bv, o[n], 0, 0, 0);
        }
    }
    u16* aob = ao + (((size_t)b << 10) + q0) * 256;
    #pragma unroll
    for (int r = 0; r < 4; r++) {
        float inv = 1.0f / l_i[r];
        #pragma unroll
        for (int n = 0; n < 16; n++)
            aob[(size_t)(quad * 4 + r) * 256 + n * 16 + row] = f2bf(o[n][r] * inv);
    }
}

// ---------------------------------------------------------------------------
extern "C" void kernel_launch(void* const* d_in, const int* in_sizes, int n_in,
                              void* d_out, int out_size, void* d_ws, size_t ws_size,
                              hipStream_t stream) {
    const float* x      = (const float*)d_in[0];
    const float* ln1_s  = (const float*)d_in[1];
    const float* ln1_b  = (const float*)d_in[2];
    const float* w_qkv  = (const float*)d_in[3];
    const float* b_qkv  = (const float*)d_in[4];
    const float* w_proj = (const float*)d_in[5];
    const float* b_proj = (const float*)d_in[6];
    const float* ln2_s  = (const float*)d_in[7];
    const float* ln2_b  = (const float*)d_in[8];
    const float* w_fc1  = (const float*)d_in[9];
    const float* b_fc1  = (const float*)d_in[10];
    const float* w_fc2  = (const float*)d_in[11];
    const float* b_fc2  = (const float*)d_in[12];
    float* out = (float*)d_out;

    // Workspace plan (u16 units unless noted). Total ~49.2 MB.
    u16* W = (u16*)d_ws;
    u16* wqkvT  = W;                           // 768*256
    u16* wprojT = wqkvT + 196608;              // 256*256
    u16* wfc1T  = wprojT + 65536;              // 128*256
    u16* wfc2T  = wfc1T + 32768;               // 256*128
    float2* st1 = (float2*)(wfc2T + 32768);    // 32768 float2
    float2* st2 = st1 + NROWS;
    u16* buf1   = (u16*)(st2 + NROWS);         // q, then attn-out (in place)
    u16* buf2   = buf1 + (size_t)NROWS * 256;  // k, then x2
    u16* buf3   = buf2 + (size_t)NROWS * 256;  // vT, then a1

    transpose_weights<<<dim3(64), dim3(256), 0, stream>>>(
        w_qkv, wqkvT, w_proj, wprojT, w_fc1, wfc1T, w_fc2, wfc2T);
    ln_stats<float><<<dim3(NROWS / 4), dim3(256), 0, stream>>>(x, st1);
    gemm_qkv<<<dim3(NROWS / 64, 12), dim3(256), 0, stream>>>(
        x, st1, ln1_s, ln1_b, wqkvT, b_qkv, buf1, buf2, buf3);
    attn_kernel<<<dim3(SEQ / 64, NBATCH), dim3(256), 0, stream>>>(
        buf1, buf2, buf3, buf1);
    gemm_proj<<<dim3(NROWS / 64, 4), dim3(256), 0, stream>>>(
        buf1, wprojT, b_proj, x, buf2);
    ln_stats<u16><<<dim3(NROWS / 4), dim3(256), 0, stream>>>(buf2, st2);
    gemm_fc1<<<dim3(NROWS / 64, 2), dim3(256), 0, stream>>>(
        buf2, st2, ln2_s, ln2_b, wfc1T, b_fc1, buf3);
    gemm_fc2<<<dim3(NROWS / 64, 4), dim3(256), 0, stream>>>(
        buf3, wfc2T, b_fc2, buf2, out);
}